// Round 5
// baseline (159.725 us; speedup 1.0000x reference)
//
#include <hip/hip_runtime.h>

#define NB 128      // batch
#define NA 100      // atoms (N)
#define KF 32       // INNER
#define NF 33       // F = INNER+1
#define NU 512      // UNITS
#define ND 3        // DEPTH

// ws layout (floats):
//   S0      : NB*NA*KF            = 409600
//   bonds   : NB*NA*NA            = 1280000   (fpPart overlays this after p2a)
//   attrAll : NB*(ND+1)*NA*KF     = 1638400
#define SZ_S0    (NB * NA * KF)
#define SZ_BONDS (NB * NA * NA)

// ---------------------------------------------------------------------------
// Phase 1: per (b,i) row: S0[b,i,f] = sum_j x[b,i,j,f] (f<32);
//          attrAll[b,0,i,f] = x[b,i,i,f]; bonds[b,i,j] = x[b,i,j,32]
// ---------------------------------------------------------------------------
__global__ __launch_bounds__(256) void p1_reduce(const float* __restrict__ x,
    float* __restrict__ S0, float* __restrict__ attrAll, float* __restrict__ bonds)
{
    const int blk = blockIdx.x;            // b*NA + i
    const int b   = blk / NA;
    const int i   = blk % NA;
    const int t   = threadIdx.x;

    __shared__ float lds[NA * NF];         // 13.2 KB
    __shared__ float red[8][KF];

    const float4* row4 = (const float4*)(x + (size_t)blk * (NA * NF));
    float4* lds4 = (float4*)lds;
    for (int idx = t; idx < (NA * NF) / 4; idx += 256) lds4[idx] = row4[idx];
    __syncthreads();

    const int g = t >> 5;                  // 0..7
    const int f = t & 31;
    float p0 = 0.f, p1 = 0.f;
    for (int j = g; j + 8 < NA; j += 16) {
        p0 += lds[j * NF + f];
        p1 += lds[(j + 8) * NF + f];
    }
    if (g < 4) p0 += lds[(96 + g) * NF + f];   // tail rows 96..99
    red[g][f] = p0 + p1;
    __syncthreads();

    if (t < KF) {
        float s = 0.f;
#pragma unroll
        for (int gg = 0; gg < 8; ++gg) s += red[gg][t];
        S0[(size_t)blk * KF + t] = s;
    } else if (t >= 64 && t < 64 + KF) {
        attrAll[(size_t)b * (ND + 1) * NA * KF + (size_t)i * KF + (t - 64)] = lds[i * NF + (t - 64)];
    } else if (t >= 128 && t < 128 + NA) {
        const int j = t - 128;
        bonds[(size_t)blk * NA + j] = lds[j * NF + KF];
    }
}

// ---------------------------------------------------------------------------
// Phase 2a: per-batch recurrence. Produces attrAll[b][d] for d=1..ND.
// ---------------------------------------------------------------------------
__global__ __launch_bounds__(256) void p2a_recur(
    const float* __restrict__ S0, const float* __restrict__ bonds,
    const float* __restrict__ W_inner, const float* __restrict__ b_inner,
    float* __restrict__ attrAll)
{
    __shared__ float S[NA * KF];      // 3200
    __shared__ float attr[NA * KF];   // 3200
    __shared__ float Wi[KF * KF];     // 1024
    __shared__ float rs[NA];

    const int b = blockIdx.x;
    const int t = threadIdx.x;

    const float4* s4 = (const float4*)(S0 + (size_t)b * NA * KF);
    const float4* a4 = (const float4*)(attrAll + (size_t)b * (ND + 1) * NA * KF);
    for (int idx = t; idx < NA * KF / 4; idx += 256) {
        ((float4*)S)[idx]    = s4[idx];
        ((float4*)attr)[idx] = a4[idx];
    }
    if (t < NA) {
        const float* bb = bonds + (size_t)b * NA * NA + t;
        float c0=0.f,c1=0.f,c2=0.f,c3=0.f,c4=0.f,c5=0.f,c6=0.f,c7=0.f;
        int j = 0;
        for (; j + 8 <= NA; j += 8) {
            c0 += bb[(j+0)*NA]; c1 += bb[(j+1)*NA];
            c2 += bb[(j+2)*NA]; c3 += bb[(j+3)*NA];
            c4 += bb[(j+4)*NA]; c5 += bb[(j+5)*NA];
            c6 += bb[(j+6)*NA]; c7 += bb[(j+7)*NA];
        }
        for (; j < NA; ++j) c0 += bb[j*NA];
        rs[t] = 1.f + (((c0+c1)+(c2+c3))+((c4+c5)+(c6+c7)));
    }
    __syncthreads();

    for (int d = 1; d <= ND; ++d) {
        if (t < KF * KF / 4)
            ((float4*)Wi)[t] = ((const float4*)(W_inner + d * KF * KF))[t];
        __syncthreads();

        float core[13];
#pragma unroll
        for (int it = 0; it < 13; ++it) {
            const int idx = t + it * 256;
            if (idx < NA * KF) {
                const int row = idx >> 5, f = idx & 31;
                float acc = b_inner[d * KF + f];
                const float* Sr = S + row * KF;
#pragma unroll
                for (int k = 0; k < KF; ++k) acc += Sr[k] * Wi[k * KF + f];
                core[it] = acc;
            }
        }
        __syncthreads();
#pragma unroll
        for (int it = 0; it < 13; ++it) {
            const int idx = t + it * 256;
            if (idx < NA * KF) {
                const int row = idx >> 5;
                const float cc  = core[it];
                const float old = attr[idx];
                attr[idx] = cc;
                S[idx] += rs[row] * (cc - old);
                attrAll[(size_t)b * (ND + 1) * NA * KF + (size_t)d * NA * KF + idx] = cc;
            }
        }
        __syncthreads();
    }
}

// ---------------------------------------------------------------------------
// Phase 2b: one block per (b,d): fpPart[d][b][u] = sum_i softmax(attr_i@Wout[d]+bout[d])[u]
// (identical to R4; launched 3x this round as a duplicate-launch timing probe)
// ---------------------------------------------------------------------------
__global__ __launch_bounds__(512, 4) void p2b_fp(
    const float* __restrict__ attrAll, const float* __restrict__ W_output,
    const float* __restrict__ b_output, float* __restrict__ fpPart)
{
    extern __shared__ float sm[];
    float* Wl    = sm;            // [32*512] = 64 KB
    float* attrL = sm + KF * NU;  // [104*32] = 13.3 KB

    const int blk  = blockIdx.x;
    const int b    = blk & (NB - 1);
    const int d    = blk >> 7;
    const int t    = threadIdx.x;
    const int lane = t & 63;
    const int w    = t >> 6;

    const float4* wo4 = (const float4*)(W_output + (size_t)d * KF * NU);
    for (int idx = t; idx < KF * NU / 4; idx += 512) ((float4*)Wl)[idx] = wo4[idx];
    const float4* a4 = (const float4*)(attrAll + ((size_t)b * (ND + 1) + d) * NA * KF);
    for (int idx = t; idx < NA * KF / 4; idx += 512) ((float4*)attrL)[idx] = a4[idx];
    if (t < (104 - NA) * KF) attrL[NA * KF + t] = 0.f;    // zero pad rows 100..103

    const float4 bv0 = *(const float4*)&b_output[d * NU + lane * 4];
    const float4 bv1 = *(const float4*)&b_output[d * NU + 256 + lane * 4];

    float fpacc[8];
#pragma unroll
    for (int c = 0; c < 8; ++c) fpacc[c] = 0.f;

    __syncthreads();

#pragma unroll
    for (int p = 0; p < 2; ++p) {
        const int r0 = p * 64 + w * 8;
        if (r0 >= NA) continue;                      // wave-uniform
        float acc[8][8];
#pragma unroll
        for (int r = 0; r < 8; ++r) {
            acc[r][0] = bv0.x; acc[r][1] = bv0.y; acc[r][2] = bv0.z; acc[r][3] = bv0.w;
            acc[r][4] = bv1.x; acc[r][5] = bv1.y; acc[r][6] = bv1.z; acc[r][7] = bv1.w;
        }
        for (int k4 = 0; k4 < KF; k4 += 4) {
#pragma unroll
            for (int kk = 0; kk < 4; ++kk) {
                const float4 w0 = *(const float4*)&Wl[(k4 + kk) * NU + lane * 4];
                const float4 w1 = *(const float4*)&Wl[(k4 + kk) * NU + 256 + lane * 4];
#pragma unroll
                for (int r = 0; r < 8; ++r) {
                    const float a = attrL[(r0 + r) * KF + k4 + kk];   // broadcast
                    acc[r][0] += a * w0.x; acc[r][1] += a * w0.y;
                    acc[r][2] += a * w0.z; acc[r][3] += a * w0.w;
                    acc[r][4] += a * w1.x; acc[r][5] += a * w1.y;
                    acc[r][6] += a * w1.z; acc[r][7] += a * w1.w;
                }
            }
        }
#pragma unroll
        for (int r = 0; r < 8; ++r) {
            if (r0 + r >= NA) continue;
            float m = acc[r][0];
#pragma unroll
            for (int c = 1; c < 8; ++c) m = fmaxf(m, acc[r][c]);
#pragma unroll
            for (int off = 32; off > 0; off >>= 1) m = fmaxf(m, __shfl_xor(m, off, 64));
            float e[8], s = 0.f;
#pragma unroll
            for (int c = 0; c < 8; ++c) { e[c] = __expf(acc[r][c] - m); s += e[c]; }
#pragma unroll
            for (int off = 32; off > 0; off >>= 1) s += __shfl_xor(s, off, 64);
            const float inv = 1.f / s;
#pragma unroll
            for (int c = 0; c < 8; ++c) fpacc[c] += e[c] * inv;
        }
    }

    // cross-wave reduce (overlay on Wl)
    __syncthreads();
    float* fp8 = Wl;
    {
        float4 f0 = {fpacc[0], fpacc[1], fpacc[2], fpacc[3]};
        float4 f1 = {fpacc[4], fpacc[5], fpacc[6], fpacc[7]};
        *(float4*)&fp8[w * NU + lane * 4]       = f0;
        *(float4*)&fp8[w * NU + 256 + lane * 4] = f1;
    }
    __syncthreads();
    float s = fp8[t];
#pragma unroll
    for (int ww = 1; ww < 8; ++ww) s += fp8[ww * NU + t];
    fpPart[((size_t)d * NB + b) * NU + t] = s;
}

// ---------------------------------------------------------------------------
// Phase 2c: out[b][u] = sum_d fpPart[d][b][u]
// ---------------------------------------------------------------------------
__global__ __launch_bounds__(512) void p2c_out(const float* __restrict__ fpPart,
                                               float* __restrict__ out)
{
    const int b = blockIdx.x, t = threadIdx.x;
    float s = 0.f;
#pragma unroll
    for (int d = 0; d <= ND; ++d) s += fpPart[((size_t)d * NB + b) * NU + t];
    out[(size_t)b * NU + t] = s;
}

// ---------------------------------------------------------------------------
extern "C" void kernel_launch(void* const* d_in, const int* in_sizes, int n_in,
                              void* d_out, int out_size, void* d_ws, size_t ws_size,
                              hipStream_t stream) {
    (void)in_sizes; (void)n_in; (void)out_size; (void)ws_size;
    const float* x        = (const float*)d_in[0];
    const float* W_inner  = (const float*)d_in[1];
    const float* b_inner  = (const float*)d_in[2];
    const float* W_output = (const float*)d_in[3];
    const float* b_output = (const float*)d_in[4];
    float* out = (float*)d_out;

    float* S0      = (float*)d_ws;
    float* bonds   = S0 + SZ_S0;
    float* attrAll = bonds + SZ_BONDS;
    float* fpPart  = bonds;               // overlay: bonds dead after p2a

    p1_reduce<<<NB * NA, 256, 0, stream>>>(x, S0, attrAll, bonds);
    p2a_recur<<<NB, 256, 0, stream>>>(S0, bonds, W_inner, b_inner, attrAll);

    const size_t smemB = (size_t)(KF * NU + 104 * KF) * sizeof(float);  // 77.3 KB
    hipFuncSetAttribute(reinterpret_cast<const void*>(p2b_fp),
                        hipFuncAttributeMaxDynamicSharedMemorySize, (int)smemB);
    // TIMING PROBE: launch p2b 3x with identical args (identical output each
    // time -> deterministic). total = rest + 3*p2b  =>  p2b = (R5 - R4)/2.
    p2b_fp<<<NB * (ND + 1), 512, smemB, stream>>>(attrAll, W_output, b_output, fpPart);
    p2b_fp<<<NB * (ND + 1), 512, smemB, stream>>>(attrAll, W_output, b_output, fpPart);
    p2b_fp<<<NB * (ND + 1), 512, smemB, stream>>>(attrAll, W_output, b_output, fpPart);

    p2c_out<<<NB, 512, 0, stream>>>(fpPart, out);
}

// Round 6
// 78.205 us; speedup vs baseline: 2.0424x; 2.0424x over previous
//
#include <hip/hip_runtime.h>

typedef __attribute__((ext_vector_type(4))) float f32x4;
typedef __attribute__((ext_vector_type(8))) short s16x8;

#define NB 128      // batch
#define NA 100      // atoms (N)
#define KF 32       // INNER
#define NF 33       // F = INNER+1
#define NU 512      // UNITS
#define ND 3        // DEPTH

#define SZ_S0    (NB * NA * KF)
#define SZ_BONDS (NB * NA * NA)

__device__ __forceinline__ unsigned short f2bf(float f) {
    unsigned int u = __float_as_uint(f);
    u = (u + 0x7fffu + ((u >> 16) & 1u)) >> 16;      // RNE
    return (unsigned short)u;
}
__device__ __forceinline__ float bf2f(unsigned short h) {
    return __uint_as_float(((unsigned int)h) << 16);
}

// ---------------------------------------------------------------------------
// Phase 1: per (b,i) row: S0[b,i,f] = sum_j x[b,i,j,f] (f<32);
//          attrAll[b,0,i,f] = x[b,i,i,f]; bonds[b,i,j] = x[b,i,j,32]
// ---------------------------------------------------------------------------
__global__ __launch_bounds__(256) void p1_reduce(const float* __restrict__ x,
    float* __restrict__ S0, float* __restrict__ attrAll, float* __restrict__ bonds)
{
    const int blk = blockIdx.x;            // b*NA + i
    const int b   = blk / NA;
    const int i   = blk % NA;
    const int t   = threadIdx.x;

    __shared__ float lds[NA * NF];         // 13.2 KB
    __shared__ float red[8][KF];

    const float4* row4 = (const float4*)(x + (size_t)blk * (NA * NF));
    float4* lds4 = (float4*)lds;
    for (int idx = t; idx < (NA * NF) / 4; idx += 256) lds4[idx] = row4[idx];
    __syncthreads();

    const int g = t >> 5;                  // 0..7
    const int f = t & 31;
    float p0 = 0.f, p1 = 0.f;
    for (int j = g; j + 8 < NA; j += 16) {
        p0 += lds[j * NF + f];
        p1 += lds[(j + 8) * NF + f];
    }
    if (g < 4) p0 += lds[(96 + g) * NF + f];   // tail rows 96..99
    red[g][f] = p0 + p1;
    __syncthreads();

    if (t < KF) {
        float s = 0.f;
#pragma unroll
        for (int gg = 0; gg < 8; ++gg) s += red[gg][t];
        S0[(size_t)blk * KF + t] = s;
    } else if (t >= 64 && t < 64 + KF) {
        attrAll[(size_t)b * (ND + 1) * NA * KF + (size_t)i * KF + (t - 64)] = lds[i * NF + (t - 64)];
    } else if (t >= 128 && t < 128 + NA) {
        const int j = t - 128;
        bonds[(size_t)blk * NA + j] = lds[j * NF + KF];
    }
}

// ---------------------------------------------------------------------------
// Phase 2a: per-batch recurrence. Produces attrAll[b][d] for d=1..ND.
// ---------------------------------------------------------------------------
__global__ __launch_bounds__(256) void p2a_recur(
    const float* __restrict__ S0, const float* __restrict__ bonds,
    const float* __restrict__ W_inner, const float* __restrict__ b_inner,
    float* __restrict__ attrAll)
{
    __shared__ float S[NA * KF];
    __shared__ float attr[NA * KF];
    __shared__ float Wi[KF * KF];
    __shared__ float rs[NA];

    const int b = blockIdx.x;
    const int t = threadIdx.x;

    const float4* s4 = (const float4*)(S0 + (size_t)b * NA * KF);
    const float4* a4 = (const float4*)(attrAll + (size_t)b * (ND + 1) * NA * KF);
    for (int idx = t; idx < NA * KF / 4; idx += 256) {
        ((float4*)S)[idx]    = s4[idx];
        ((float4*)attr)[idx] = a4[idx];
    }
    if (t < NA) {
        const float* bb = bonds + (size_t)b * NA * NA + t;
        float c0=0.f,c1=0.f,c2=0.f,c3=0.f,c4=0.f,c5=0.f,c6=0.f,c7=0.f;
        int j = 0;
        for (; j + 8 <= NA; j += 8) {
            c0 += bb[(j+0)*NA]; c1 += bb[(j+1)*NA];
            c2 += bb[(j+2)*NA]; c3 += bb[(j+3)*NA];
            c4 += bb[(j+4)*NA]; c5 += bb[(j+5)*NA];
            c6 += bb[(j+6)*NA]; c7 += bb[(j+7)*NA];
        }
        for (; j < NA; ++j) c0 += bb[j*NA];
        rs[t] = 1.f + (((c0+c1)+(c2+c3))+((c4+c5)+(c6+c7)));
    }
    __syncthreads();

    for (int d = 1; d <= ND; ++d) {
        if (t < KF * KF / 4)
            ((float4*)Wi)[t] = ((const float4*)(W_inner + d * KF * KF))[t];
        __syncthreads();

        float core[13];
#pragma unroll
        for (int it = 0; it < 13; ++it) {
            const int idx = t + it * 256;
            if (idx < NA * KF) {
                const int row = idx >> 5, f = idx & 31;
                float acc = b_inner[d * KF + f];
                const float* Sr = S + row * KF;
#pragma unroll
                for (int k = 0; k < KF; ++k) acc += Sr[k] * Wi[k * KF + f];
                core[it] = acc;
            }
        }
        __syncthreads();
#pragma unroll
        for (int it = 0; it < 13; ++it) {
            const int idx = t + it * 256;
            if (idx < NA * KF) {
                const int row = idx >> 5;
                const float cc  = core[it];
                const float old = attr[idx];
                attr[idx] = cc;
                S[idx] += rs[row] * (cc - old);
                attrAll[(size_t)b * (ND + 1) * NA * KF + (size_t)d * NA * KF + idx] = cc;
            }
        }
        __syncthreads();
    }
}

// ---------------------------------------------------------------------------
// pW: split W_output into bf16 hi/lo, stored in B-fragment layout:
//   WB[d][tile=col>>4][kg=k>>3][col&15][k&7]   (512 ushorts per tile)
// Lane l of a wave then reads its B-frag (col=l&15, k=(l>>4)*8+j) as ONE
// contiguous b128: byte = tile*1024 + (l>>4)*256 + (l&15)*16.
// ---------------------------------------------------------------------------
__global__ __launch_bounds__(256) void pW_prep(const float* __restrict__ W_output,
    unsigned short* __restrict__ WBh, unsigned short* __restrict__ WBl)
{
    const int i = blockIdx.x * 256 + threadIdx.x;    // 65536 total
    const int d = i >> 14, rem = i & 16383, k = rem >> 9, col = rem & 511;
    const float v = W_output[(size_t)d * (KF * NU) + (size_t)k * NU + col];
    const unsigned short hi = f2bf(v);
    const unsigned short lo = f2bf(v - bf2f(hi));
    const int dst = d * 16384 + (col >> 4) * 512 + (k >> 3) * 128 + (col & 15) * 8 + (k & 7);
    WBh[dst] = hi;
    WBl[dst] = lo;
}

// ---------------------------------------------------------------------------
// Phase 2b (MFMA): one block per (b,d), 448 thr = 7 waves; wave w owns row-tile
// w (rows w*16..w*16+15), all 512 cols = 32 col-tiles. Logits via bf16x3
// split-fp32 MFMA (K=32 in one instruction), softmax in-register on the
// verified C layout (col=lane&15, row=(lane>>4)*4+reg).
// ---------------------------------------------------------------------------
__global__ __launch_bounds__(448) void p2b_mfma(
    const float* __restrict__ attrAll,
    const unsigned short* __restrict__ WBh_g, const unsigned short* __restrict__ WBl_g,
    const float* __restrict__ b_output, float* __restrict__ fpPart)
{
    extern __shared__ unsigned char smraw[];
    unsigned short* WBh  = (unsigned short*)smraw;        // 32768 B
    unsigned short* WBl  = WBh + 16384;                   // 32768 B
    unsigned short* aAh  = WBl + 16384;                   //  7168 B
    unsigned short* aAl  = aAh + 3584;                    //  7168 B
    float*          biasL= (float*)(aAl + 3584);          //  2048 B   (total 80 KB)
    float*          fpw  = (float*)aAh;                   // overlay, 14336 B

    const int blk = blockIdx.x;
    const int b   = blk & (NB - 1);
    const int d   = blk >> 7;
    const int t   = threadIdx.x;
    const int l   = t & 63;
    const int w   = t >> 6;                               // 0..6

    // stage W hi/lo (2048 float4 each, coalesced)
    for (int i = t; i < 2048; i += 448) ((float4*)WBh)[i] = ((const float4*)WBh_g)[d * 2048 + i];
    for (int i = t; i < 2048; i += 448) ((float4*)WBl)[i] = ((const float4*)WBl_g)[d * 2048 + i];
    for (int i = t; i < NU; i += 448)   biasL[i] = b_output[d * NU + i];

    // stage attr -> bf16 hi/lo in A-fragment layout [tile][kg][row16][8k]
    const float* A = attrAll + ((size_t)b * (ND + 1) + d) * (NA * KF);
    for (int i = t; i < 3584; i += 448) {                 // 112 rows x 32 k
        const int gr = i >> 5, k = i & 31;
        const float v = (gr < NA) ? A[gr * KF + k] : 0.f;
        const unsigned short hi = f2bf(v);
        const unsigned short lo = f2bf(v - bf2f(hi));
        const int dst = ((gr >> 4) * 4 + (k >> 3)) * 128 + (gr & 15) * 8 + (k & 7);
        aAh[dst] = hi;
        aAl[dst] = lo;
    }
    __syncthreads();

    // A-fragments for this wave's row-tile (1 contiguous b128 each)
    const int aoff = (w * 4 + (l >> 4)) * 128 + (l & 15) * 8;
    const s16x8 ah = *(const s16x8*)&aAh[aoff];
    const s16x8 al = *(const s16x8*)&aAl[aoff];

    f32x4 acc[32];
#pragma unroll
    for (int tt = 0; tt < 32; ++tt) {
        const int boff = tt * 512 + (l >> 4) * 128 + (l & 15) * 8;
        const s16x8 bh = *(const s16x8*)&WBh[boff];
        const s16x8 bl = *(const s16x8*)&WBl[boff];
        f32x4 c = {0.f, 0.f, 0.f, 0.f};
        c = __builtin_amdgcn_mfma_f32_16x16x32_bf16(ah, bh, c, 0, 0, 0);
        c = __builtin_amdgcn_mfma_f32_16x16x32_bf16(ah, bl, c, 0, 0, 0);
        c = __builtin_amdgcn_mfma_f32_16x16x32_bf16(al, bh, c, 0, 0, 0);
        const float bias = biasL[tt * 16 + (l & 15)];
#pragma unroll
        for (int r = 0; r < 4; ++r) c[r] += bias;
        acc[tt] = c;
    }

    // softmax per row (row lives across the 16 lanes sharing l>>4)
    float mx[4] = {-3.4e38f, -3.4e38f, -3.4e38f, -3.4e38f};
#pragma unroll
    for (int tt = 0; tt < 32; ++tt)
#pragma unroll
        for (int r = 0; r < 4; ++r) mx[r] = fmaxf(mx[r], acc[tt][r]);
#pragma unroll
    for (int off = 1; off <= 8; off <<= 1)
#pragma unroll
        for (int r = 0; r < 4; ++r) mx[r] = fmaxf(mx[r], __shfl_xor(mx[r], off, 64));

    float sum[4] = {0.f, 0.f, 0.f, 0.f};
#pragma unroll
    for (int tt = 0; tt < 32; ++tt)
#pragma unroll
        for (int r = 0; r < 4; ++r) {
            const float e = __expf(acc[tt][r] - mx[r]);
            acc[tt][r] = e;
            sum[r] += e;
        }
#pragma unroll
    for (int off = 1; off <= 8; off <<= 1)
#pragma unroll
        for (int r = 0; r < 4; ++r) sum[r] += __shfl_xor(sum[r], off, 64);

    float inv[4];
#pragma unroll
    for (int r = 0; r < 4; ++r) {
        const int grow = w * 16 + (l >> 4) * 4 + r;
        inv[r] = (grow < NA) ? 1.f / sum[r] : 0.f;       // mask pad rows
    }

    // fp contribution per column; reduce the 4 row-groups via shfl
#pragma unroll
    for (int tt = 0; tt < 32; ++tt) {
        float f = acc[tt][0] * inv[0] + acc[tt][1] * inv[1]
                + acc[tt][2] * inv[2] + acc[tt][3] * inv[3];
        f += __shfl_xor(f, 16, 64);
        f += __shfl_xor(f, 32, 64);
        if (l < 16) fpw[w * NU + tt * 16 + l] = f;
    }
    __syncthreads();

    for (int u = t; u < NU; u += 448) {
        float s = 0.f;
#pragma unroll
        for (int ww = 0; ww < 7; ++ww) s += fpw[ww * NU + u];
        fpPart[((size_t)d * NB + b) * NU + u] = s;
    }
}

// ---------------------------------------------------------------------------
// Phase 2c: out[b][u] = sum_d fpPart[d][b][u]
// ---------------------------------------------------------------------------
__global__ __launch_bounds__(512) void p2c_out(const float* __restrict__ fpPart,
                                               float* __restrict__ out)
{
    const int b = blockIdx.x, t = threadIdx.x;
    float s = 0.f;
#pragma unroll
    for (int d = 0; d <= ND; ++d) s += fpPart[((size_t)d * NB + b) * NU + t];
    out[(size_t)b * NU + t] = s;
}

// ---------------------------------------------------------------------------
extern "C" void kernel_launch(void* const* d_in, const int* in_sizes, int n_in,
                              void* d_out, int out_size, void* d_ws, size_t ws_size,
                              hipStream_t stream) {
    (void)in_sizes; (void)n_in; (void)out_size; (void)ws_size;
    const float* x        = (const float*)d_in[0];
    const float* W_inner  = (const float*)d_in[1];
    const float* b_inner  = (const float*)d_in[2];
    const float* W_output = (const float*)d_in[3];
    const float* b_output = (const float*)d_in[4];
    float* out = (float*)d_out;

    float* S0      = (float*)d_ws;
    float* bonds   = S0 + SZ_S0;
    float* attrAll = bonds + SZ_BONDS;
    float* fpPart  = bonds;                       // overlay: bonds dead after p2a
    unsigned short* WBh = (unsigned short*)S0;    // overlay: S0 dead after p2a
    unsigned short* WBl = WBh + 65536;            // 256 KB total << S0's 1.6 MB

    p1_reduce<<<NB * NA, 256, 0, stream>>>(x, S0, attrAll, bonds);
    p2a_recur<<<NB, 256, 0, stream>>>(S0, bonds, W_inner, b_inner, attrAll);
    pW_prep<<<256, 256, 0, stream>>>(W_output, WBh, WBl);

    const size_t smemB = 81920;                   // 80 KB
    hipFuncSetAttribute(reinterpret_cast<const void*>(p2b_mfma),
                        hipFuncAttributeMaxDynamicSharedMemorySize, (int)smemB);
    p2b_mfma<<<NB * (ND + 1), 448, smemB, stream>>>(attrAll, WBh, WBl, b_output, fpPart);
    p2c_out<<<NB, 512, 0, stream>>>(fpPart, out);
}